// Round 1
// baseline (343.852 us; speedup 1.0000x reference)
//
#include <hip/hip_runtime.h>
#include <math.h>

#define EPS 1e-8f

// ---------------- prep kernels ----------------

// Transpose W_enc [24][1024] -> wt [1024][24] (k-major, contiguous 24 floats per k)
__global__ void prep_transpose(const float* __restrict__ W_enc, float* __restrict__ wt) {
    int i = blockIdx.x * 256 + threadIdx.x;          // 0 .. 24575
    if (i < 24576) {
        int k = i / 24, l = i - k * 24;
        wt[i] = W_enc[l * 1024 + k];
    }
}

// G[l][m] = sum_d Wd[d][l]*Wd[d][m];  h[l] = sum_d Wd[d][l]*bd[d];  bb = ||bd||^2
__global__ void prep_gram(const float* __restrict__ Wd, const float* __restrict__ bd,
                          float* __restrict__ G, float* __restrict__ h, float* __restrict__ bb) {
    int b = blockIdx.x;            // 0..600
    int lane = threadIdx.x;        // 64 threads
    float s = 0.f;
    if (b < 576) {
        int l = b / 24, m = b - (b / 24) * 24;
        for (int d = lane; d < 1024; d += 64) s = fmaf(Wd[d * 24 + l], Wd[d * 24 + m], s);
    } else if (b < 600) {
        int l = b - 576;
        for (int d = lane; d < 1024; d += 64) s = fmaf(Wd[d * 24 + l], bd[d], s);
    } else {
        for (int d = lane; d < 1024; d += 64) s = fmaf(bd[d], bd[d], s);
    }
    for (int off = 32; off; off >>= 1) s += __shfl_down(s, off);
    if (lane == 0) {
        if (b < 576) G[b] = s;
        else if (b < 600) h[b - 576] = s;
        else *bb = s;
    }
}

// ---------------- main kernel ----------------
// Block = 256 threads (4 waves), 64 rows per block, lane = row.
// Wave w owns k-range [256w, 256w+256) (encode) and d-range [256w, 256w+256) (decode).

constexpr int LD_TILE   = 33;              // 32 + 1 pad -> bank-free
constexpr int TILE_F    = 64 * LD_TILE;    // 2112 floats per wave
constexpr int COMB_BASE = 4 * TILE_F;      // 8448
constexpr int COMB_LD   = 65;
constexpr int SMEM_F    = COMB_BASE + 4 * 25 * COMB_LD;  // 14948 floats = 59792 B

__global__ __launch_bounds__(256, 2)
void leech_main(const float* __restrict__ data,
                const float* __restrict__ b_enc,
                const float* __restrict__ Wd,
                const float* __restrict__ b_dec,
                const float* __restrict__ ecs_p,
                const float* __restrict__ ep_p,
                const float* __restrict__ wt,
                const float* __restrict__ G,
                const float* __restrict__ h,
                const float* __restrict__ bbp,
                float* __restrict__ out)
{
    __shared__ float smem[SMEM_F];
    const int tid = threadIdx.x;
    const int w = tid >> 6;         // wave id 0..3
    const int r = tid & 63;         // lane = row within block
    const int rowbase = blockIdx.x * 64;

    float* tile = smem + w * TILE_F;

    // -------- encode: proj partials over this wave's k-range --------
    float proj[24];
#pragma unroll
    for (int l = 0; l < 24; ++l) proj[l] = 0.f;
    float ssq = 0.f;

    const int lrow = r >> 3;        // 0..7
    const int lk   = (r & 7) * 4;   // 0,4,...,28

    for (int sc = 0; sc < 8; ++sc) {
        const int k0 = w * 256 + sc * 32;
        // stage 64 rows x 32 k into wave-private padded tile (coalesced loads)
#pragma unroll
        for (int it = 0; it < 8; ++it) {
            const int row = it * 8 + lrow;
            const float4 v = *reinterpret_cast<const float4*>(
                data + (size_t)(rowbase + row) * 1024 + k0 + lk);
            float* t = tile + row * LD_TILE + lk;
            t[0] = v.x; t[1] = v.y; t[2] = v.z; t[3] = v.w;
        }
        __syncthreads();
        const float* xrow = tile + r * LD_TILE;
        const int kofs = __builtin_amdgcn_readfirstlane(k0);
#pragma unroll 4
        for (int kk = 0; kk < 32; ++kk) {
            const float x = xrow[kk];
            ssq = fmaf(x, x, ssq);
            const float* wp = wt + (size_t)(kofs + kk) * 24;   // uniform -> s_load
#pragma unroll
            for (int l = 0; l < 24; ++l)
                proj[l] = fmaf(wp[l], x, proj[l]);
        }
        __syncthreads();
    }

    // -------- combine partials across the 4 waves --------
#pragma unroll
    for (int l = 0; l < 24; ++l)
        smem[COMB_BASE + (w * 25 + l) * COMB_LD + r] = proj[l];
    smem[COMB_BASE + (w * 25 + 24) * COMB_LD + r] = ssq;
    __syncthreads();

    float p[24];
#pragma unroll
    for (int l = 0; l < 24; ++l)
        p[l] = (smem[COMB_BASE + (0 * 25 + l) * COMB_LD + r] +
                smem[COMB_BASE + (1 * 25 + l) * COMB_LD + r]) +
               (smem[COMB_BASE + (2 * 25 + l) * COMB_LD + r] +
                smem[COMB_BASE + (3 * 25 + l) * COMB_LD + r]);
    const float ss = (smem[COMB_BASE + (0 * 25 + 24) * COMB_LD + r] +
                      smem[COMB_BASE + (1 * 25 + 24) * COMB_LD + r]) +
                     (smem[COMB_BASE + (2 * 25 + 24) * COMB_LD + r] +
                      smem[COMB_BASE + (3 * 25 + 24) * COMB_LD + r]);

    // -------- per-row epilogue (all uniform weights via s_load) --------
    const float ecs = ecs_p[0];
    const float ep  = ep_p[0];
    const float in_e = sqrtf(ss);

    float lp[24]; float oe = 0.f;
#pragma unroll
    for (int l = 0; l < 24; ++l) {
        const float pp = p[l] + b_enc[l];
        const float q = rintf(pp / ecs) * ecs;   // half-even, exact div to match np
        lp[l] = q;
        oe = fmaf(q, q, oe);
    }
    const float s1 = in_e / (sqrtf(oe) + EPS) * ep;

    float c[24]; float ie = 0.f;
#pragma unroll
    for (int l = 0; l < 24; ++l) {
        const float lat = lp[l] * s1;
        ie = fmaf(lat, lat, ie);
        c[l] = (fabsf(lat) > ecs) ? lat : 0.f;
    }
    const float in_e2 = sqrtf(ie);

    // ||Wd c + b_dec||^2 = c^T G c + 2 h^T c + bb   (Gram trick, no decode recompute)
    float qacc = bbp[0];
#pragma unroll
    for (int l = 0; l < 24; ++l) {
        float s = 2.f * h[l];
#pragma unroll
        for (int m = 0; m < 24; ++m)
            s = fmaf(G[l * 24 + m], c[m], s);
        qacc = fmaf(s, c[l], qacc);
    }
    const float out_e2 = sqrtf(fmaxf(qacc, 0.f));
    const float s2 = in_e2 / (out_e2 + EPS) * ep;

    // -------- decode: this wave's d-range, tile transpose, coalesced stores --------
    for (int sc = 0; sc < 8; ++sc) {
        const int d0 = __builtin_amdgcn_readfirstlane(w * 256 + sc * 32);
        __syncthreads();   // previous store-phase reads done before overwrite
        float* trow = tile + r * LD_TILE;
#pragma unroll 4
        for (int dd = 0; dd < 32; ++dd) {
            const int d = d0 + dd;
            const float* wr = Wd + d * 24;       // uniform -> s_load
            float acc = b_dec[d];
#pragma unroll
            for (int l = 0; l < 24; ++l)
                acc = fmaf(wr[l], c[l], acc);
            trow[dd] = acc * s2;
        }
        __syncthreads();
#pragma unroll
        for (int it = 0; it < 8; ++it) {
            const int row = it * 8 + lrow;
            const float* t = tile + row * LD_TILE + lk;
            float4 v; v.x = t[0]; v.y = t[1]; v.z = t[2]; v.w = t[3];
            *reinterpret_cast<float4*>(out + (size_t)(rowbase + row) * 1024 + d0 + lk) = v;
        }
    }
}

// ---------------- launcher ----------------

extern "C" void kernel_launch(void* const* d_in, const int* in_sizes, int n_in,
                              void* d_out, int out_size, void* d_ws, size_t ws_size,
                              hipStream_t stream) {
    const float* data  = (const float*)d_in[0];
    const float* W_enc = (const float*)d_in[1];
    const float* b_enc = (const float*)d_in[2];
    const float* W_dec = (const float*)d_in[3];
    const float* b_dec = (const float*)d_in[4];
    const float* ecs   = (const float*)d_in[5];
    const float* ep    = (const float*)d_in[6];
    float* out = (float*)d_out;

    float* ws = (float*)d_ws;
    float* wt = ws;                 // 24576 floats: W_enc transposed, k-major
    float* G  = ws + 24576;         // 576
    float* h  = ws + 25152;         // 24
    float* bb = ws + 25176;         // 1

    const int rows = in_sizes[0] / 1024;    // 32768

    hipLaunchKernelGGL(prep_transpose, dim3(96), dim3(256), 0, stream, W_enc, wt);
    hipLaunchKernelGGL(prep_gram, dim3(601), dim3(64), 0, stream, W_dec, b_dec, G, h, bb);
    hipLaunchKernelGGL(leech_main, dim3(rows / 64), dim3(256), 0, stream,
                       data, b_enc, W_dec, b_dec, ecs, ep, wt, G, h, bb, out);
}

// Round 2
// 323.675 us; speedup vs baseline: 1.0623x; 1.0623x over previous
//
#include <hip/hip_runtime.h>
#include <math.h>

#define EPS 1e-8f

// ---------------- prep kernel (fused transpose + Gram) ----------------
// blocks 0..383   : transpose W_enc [24][1024] -> wt [1024][24]  (64 thr each)
// blocks 384..959 : G[l][m] = sum_d Wd[d][l]*Wd[d][m]
// blocks 960..983 : h[l] = sum_d Wd[d][l]*bd[d]
// block  984      : bb = ||bd||^2
__global__ void prep_all(const float* __restrict__ W_enc,
                         const float* __restrict__ Wd, const float* __restrict__ bd,
                         float* __restrict__ wt, float* __restrict__ G,
                         float* __restrict__ h, float* __restrict__ bb) {
    int b = blockIdx.x;
    int lane = threadIdx.x;     // 64
    if (b < 384) {
        int i = b * 64 + lane;  // 0..24575
        int k = i / 24, l = i - k * 24;
        wt[i] = W_enc[l * 1024 + k];
        return;
    }
    b -= 384;
    float s = 0.f;
    if (b < 576) {
        int l = b / 24, m = b - (b / 24) * 24;
        for (int d = lane; d < 1024; d += 64) s = fmaf(Wd[d * 24 + l], Wd[d * 24 + m], s);
    } else if (b < 600) {
        int l = b - 576;
        for (int d = lane; d < 1024; d += 64) s = fmaf(Wd[d * 24 + l], bd[d], s);
    } else {
        for (int d = lane; d < 1024; d += 64) s = fmaf(bd[d], bd[d], s);
    }
    for (int off = 32; off; off >>= 1) s += __shfl_down(s, off);
    if (lane == 0) {
        if (b < 576) G[b] = s;
        else if (b < 600) h[b - 576] = s;
        else *bb = s;
    }
}

// ---------------- main kernel ----------------
// Block = 256 threads (4 waves), 64 rows per block, lane = row.
// Wave w owns k-range [256w,256w+256) (encode) and d-range (decode).
// Tiles are WAVE-PRIVATE: same-wave LDS ops are in-order -> no barriers in
// the chunk loops. Exactly 2 __syncthreads (around the cross-wave combine).
// Combine scratch (25x64 floats/wave) overlays the wave's OWN tile region.

constexpr int LD_TILE = 33;            // 32+1 pad -> (r+kk)%32 banks, 2/bank = free
constexpr int TILE_F  = 64 * LD_TILE;  // 2112 floats per wave
constexpr int SMEM_F  = 4 * TILE_F;    // 8448 floats = 33792 B -> 4 blocks/CU

__global__ __launch_bounds__(256, 4)
void leech_main(const float* __restrict__ data,
                const float* __restrict__ b_enc,
                const float* __restrict__ Wd,
                const float* __restrict__ b_dec,
                const float* __restrict__ ecs_p,
                const float* __restrict__ ep_p,
                const float* __restrict__ wt,
                const float* __restrict__ G,
                const float* __restrict__ h,
                const float* __restrict__ bbp,
                float* __restrict__ out)
{
    __shared__ float smem[SMEM_F];
    const int tid = threadIdx.x;
    const int w = tid >> 6;
    const int r = tid & 63;
    const int rowbase = blockIdx.x * 64;

    float* tile = smem + w * TILE_F;

    const int lrow = r >> 3;        // 0..7
    const int lk   = (r & 7) * 4;   // 0,4,...,28

    // -------- encode: proj partials over this wave's k-range --------
    float proj[24];
#pragma unroll
    for (int l = 0; l < 24; ++l) proj[l] = 0.f;
    float ssq = 0.f;

    const int kw = __builtin_amdgcn_readfirstlane((tid >> 6) * 256);

    float4 buf[8];
#pragma unroll
    for (int it = 0; it < 8; ++it)
        buf[it] = *reinterpret_cast<const float4*>(
            data + (size_t)(rowbase + it * 8 + lrow) * 1024 + kw + lk);

    for (int sc = 0; sc < 8; ++sc) {
        // stage current chunk into wave-private padded tile
#pragma unroll
        for (int it = 0; it < 8; ++it) {
            float* t = tile + (it * 8 + lrow) * LD_TILE + lk;
            t[0] = buf[it].x; t[1] = buf[it].y; t[2] = buf[it].z; t[3] = buf[it].w;
        }
        // prefetch next chunk (issued before compute; latency hidden)
        if (sc < 7) {
            const int k0n = kw + (sc + 1) * 32;
#pragma unroll
            for (int it = 0; it < 8; ++it)
                buf[it] = *reinterpret_cast<const float4*>(
                    data + (size_t)(rowbase + it * 8 + lrow) * 1024 + k0n + lk);
        }
        // compute on current chunk (same-wave LDS in-order: no barrier)
        const float* xrow = tile + r * LD_TILE;
        const int kofs = __builtin_amdgcn_readfirstlane(kw + sc * 32);
#pragma unroll 8
        for (int kk = 0; kk < 32; ++kk) {
            const float x = xrow[kk];
            ssq = fmaf(x, x, ssq);
            const float* wp = wt + (size_t)(kofs + kk) * 24;   // uniform -> s_load
#pragma unroll
            for (int l = 0; l < 24; ++l)
                proj[l] = fmaf(wp[l], x, proj[l]);
        }
    }

    // -------- combine partials across the 4 waves (overlay own tile) --------
#pragma unroll
    for (int l = 0; l < 24; ++l)
        smem[w * TILE_F + l * 64 + r] = proj[l];
    smem[w * TILE_F + 24 * 64 + r] = ssq;
    __syncthreads();

    float p[24];
#pragma unroll
    for (int l = 0; l < 24; ++l)
        p[l] = (smem[0 * TILE_F + l * 64 + r] + smem[1 * TILE_F + l * 64 + r]) +
               (smem[2 * TILE_F + l * 64 + r] + smem[3 * TILE_F + l * 64 + r]);
    const float ss = (smem[0 * TILE_F + 24 * 64 + r] + smem[1 * TILE_F + 24 * 64 + r]) +
                     (smem[2 * TILE_F + 24 * 64 + r] + smem[3 * TILE_F + 24 * 64 + r]);
    __syncthreads();   // all combine reads done before decode overwrites tiles

    // -------- per-row epilogue --------
    const float ecs = ecs_p[0];
    const float ep  = ep_p[0];
    const float in_e = sqrtf(ss);

    float lp[24]; float oe = 0.f;
#pragma unroll
    for (int l = 0; l < 24; ++l) {
        const float pp = p[l] + b_enc[l];
        const float q = rintf(pp / ecs) * ecs;   // half-even, exact div to match np
        lp[l] = q;
        oe = fmaf(q, q, oe);
    }
    const float s1 = in_e / (sqrtf(oe) + EPS) * ep;

    float c[24]; float ie = 0.f;
#pragma unroll
    for (int l = 0; l < 24; ++l) {
        const float lat = lp[l] * s1;
        ie = fmaf(lat, lat, ie);
        c[l] = (fabsf(lat) > ecs) ? lat : 0.f;
    }
    const float in_e2 = sqrtf(ie);

    // ||Wd c + b_dec||^2 = c^T G c + 2 h^T c + bb
    float qacc = bbp[0];
#pragma unroll
    for (int l = 0; l < 24; ++l) {
        float s = 2.f * h[l];
#pragma unroll
        for (int m = 0; m < 24; ++m)
            s = fmaf(G[l * 24 + m], c[m], s);
        qacc = fmaf(s, c[l], qacc);
    }
    const float out_e2 = sqrtf(fmaxf(qacc, 0.f));
    const float s2 = in_e2 / (out_e2 + EPS) * ep;

    // -------- decode: wave-private transpose tiles, no barriers --------
    for (int sc = 0; sc < 8; ++sc) {
        const int d0 = __builtin_amdgcn_readfirstlane(kw + sc * 32);
        float* trow = tile + r * LD_TILE;
#pragma unroll 4
        for (int dd = 0; dd < 32; ++dd) {
            const int d = d0 + dd;
            const float* wr = Wd + d * 24;       // uniform -> s_load
            float acc = b_dec[d];
#pragma unroll
            for (int l = 0; l < 24; ++l)
                acc = fmaf(wr[l], c[l], acc);
            trow[dd] = acc * s2;
        }
        // same-wave LDS in-order: reads below see this wave's writes above
#pragma unroll
        for (int it = 0; it < 8; ++it) {
            const float* t = tile + (it * 8 + lrow) * LD_TILE + lk;
            float4 v; v.x = t[0]; v.y = t[1]; v.z = t[2]; v.w = t[3];
            *reinterpret_cast<float4*>(
                out + (size_t)(rowbase + it * 8 + lrow) * 1024 + d0 + lk) = v;
        }
    }
}

// ---------------- launcher ----------------

extern "C" void kernel_launch(void* const* d_in, const int* in_sizes, int n_in,
                              void* d_out, int out_size, void* d_ws, size_t ws_size,
                              hipStream_t stream) {
    const float* data  = (const float*)d_in[0];
    const float* W_enc = (const float*)d_in[1];
    const float* b_enc = (const float*)d_in[2];
    const float* W_dec = (const float*)d_in[3];
    const float* b_dec = (const float*)d_in[4];
    const float* ecs   = (const float*)d_in[5];
    const float* ep    = (const float*)d_in[6];
    float* out = (float*)d_out;

    float* ws = (float*)d_ws;
    float* wt = ws;                 // 24576 floats: W_enc transposed, k-major
    float* G  = ws + 24576;         // 576
    float* h  = ws + 25152;         // 24
    float* bb = ws + 25176;         // 1

    const int rows = in_sizes[0] / 1024;    // 32768

    hipLaunchKernelGGL(prep_all, dim3(985), dim3(64), 0, stream,
                       W_enc, W_dec, b_dec, wt, G, h, bb);
    hipLaunchKernelGGL(leech_main, dim3(rows / 64), dim3(256), 0, stream,
                       data, b_enc, W_dec, b_dec, ecs, ep, wt, G, h, bb, out);
}